// Round 1
// baseline (115.721 us; speedup 1.0000x reference)
//
#include <hip/hip_runtime.h>
#include <hip/hip_bf16.h>

// Problem constants (from reference): B=2, C=64, N=16384, K=16, C_OUT=64
// out[b,o,n] = relu( max_k( u[b,e1[b,n,k],o] + v[b,e0[b,n,k],o] ) + G[b,o] )
//   u = (W1-W2)^T-transform of x per node, v = W2-transform, G = W3*mean(x)+bias
//
// Workspace layout (needs ~8.26 MiB):
//   [0, 4Mi)      u  : _Float16 [B][N][64]
//   [4Mi, 8Mi)    v  : _Float16 [B][N][64]
//   [8Mi, ...)    g  : float[128] (per b,c mean), then G : float[128]

#define NNODES 16384
#define NCH 64

// ---------- K1: per-(b,c) mean over N ----------
__global__ __launch_bounds__(256) void mean_kernel(const float* __restrict__ x,
                                                   float* __restrict__ g) {
  int row = blockIdx.x;  // 0..127 = b*64+c
  const float4* x4 = (const float4*)(x + (size_t)row * NNODES);
  int t = threadIdx.x;
  float s = 0.f;
#pragma unroll
  for (int i = 0; i < 16; ++i) {
    float4 q = x4[t + i * 256];
    s += (q.x + q.y) + (q.z + q.w);
  }
#pragma unroll
  for (int off = 32; off > 0; off >>= 1) s += __shfl_down(s, off, 64);
  __shared__ float wsum[4];
  int lane = t & 63, wv = t >> 6;
  if (lane == 0) wsum[wv] = s;
  __syncthreads();
  if (t == 0) g[row] = (wsum[0] + wsum[1] + wsum[2] + wsum[3]) * (1.0f / 16384.0f);
}

// ---------- K2: G[b,o] = sum_c W3[o,c]*g[b,c] + bias[o] ----------
__global__ __launch_bounds__(128) void gmat_kernel(const float* __restrict__ W,
                                                   const float* __restrict__ bias,
                                                   const float* __restrict__ g,
                                                   float* __restrict__ G) {
  int t = threadIdx.x;  // 0..127 = b*64+o
  int b = t >> 6, o = t & 63;
  float s = bias[o];
  const float* w3 = W + o * 192 + 128;
  const float* gb = g + b * 64;
#pragma unroll
  for (int c = 0; c < 64; ++c) s += w3[c] * gb[c];
  G[t] = s;
}

// ---------- K3: u/v node transform ----------
// grid = B * (N/32) = 1024 blocks, 256 threads (4 waves), wave handles 8 nodes,
// lanes over output channel o. A/Bm staged transposed in LDS: A[c][lane] reads
// are stride-1 across lanes -> conflict-free. x reads are wave-uniform float4
// (scalar-load eligible; all __restrict__).
__global__ __launch_bounds__(256) void uv_kernel(const float* __restrict__ x,
                                                 const float* __restrict__ W,
                                                 _Float16* __restrict__ u,
                                                 _Float16* __restrict__ v) {
  __shared__ float A[64][64];   // A[c][o]  = W1[o][c] - W2[o][c]
  __shared__ float Bm[64][64];  // Bm[c][o] = W2[o][c]
  int t = threadIdx.x;
  {
    int o = t & 63, c0 = (t >> 6) * 16;
    const float* wr = W + o * 192;
#pragma unroll
    for (int i = 0; i < 16; ++i) {
      int c = c0 + i;
      float w1 = wr[c], w2 = wr[64 + c];
      A[c][o] = w1 - w2;
      Bm[c][o] = w2;
    }
  }
  __syncthreads();
  int lane = t & 63;
  int wv = __builtin_amdgcn_readfirstlane(t >> 6);
  int blk = blockIdx.x;          // 0..1023
  int b = blk >> 9;              // 512 blocks per batch
  int m0 = (blk & 511) * 32 + wv * 8;  // wave's 8 nodes
  const float* xb = x + (size_t)b * (NCH * NNODES) + m0;
  float aU[8], aV[8];
#pragma unroll
  for (int i = 0; i < 8; ++i) { aU[i] = 0.f; aV[i] = 0.f; }
#pragma unroll 4
  for (int c = 0; c < 64; ++c) {
    float a = A[c][lane];
    float bb = Bm[c][lane];
    const float4* xr = (const float4*)(xb + (size_t)c * NNODES);
    float4 q0 = xr[0];
    float4 q1 = xr[1];
    aU[0] += a * q0.x; aV[0] += bb * q0.x;
    aU[1] += a * q0.y; aV[1] += bb * q0.y;
    aU[2] += a * q0.z; aV[2] += bb * q0.z;
    aU[3] += a * q0.w; aV[3] += bb * q0.w;
    aU[4] += a * q1.x; aV[4] += bb * q1.x;
    aU[5] += a * q1.y; aV[5] += bb * q1.y;
    aU[6] += a * q1.z; aV[6] += bb * q1.z;
    aU[7] += a * q1.w; aV[7] += bb * q1.w;
  }
  _Float16* ub = u + ((size_t)b * NNODES + m0) * NCH + lane;
  _Float16* vb = v + ((size_t)b * NNODES + m0) * NCH + lane;
#pragma unroll
  for (int i = 0; i < 8; ++i) {
    ub[i * NCH] = (_Float16)aU[i];
    vb[i * NCH] = (_Float16)aV[i];
  }
}

// ---------- K4: gather + max + relu, transpose to [b][o][n] ----------
// grid = B * (N/32) = 1024 blocks, 256 threads (4 waves), wave handles 8 n's,
// lanes over o. Edge indices are wave-uniform -> scalar loads. Gather loads
// are 128B coalesced per wave. LDS transpose (pitch 33) for coalesced output.
__global__ __launch_bounds__(256) void gather_kernel(const int* __restrict__ ei,
                                                     const _Float16* __restrict__ u,
                                                     const _Float16* __restrict__ v,
                                                     const float* __restrict__ G,
                                                     float* __restrict__ out) {
  __shared__ float tile[64][33];
  int t = threadIdx.x;
  int lane = t & 63;
  int wv = __builtin_amdgcn_readfirstlane(t >> 6);
  int blk = blockIdx.x;  // 0..1023
  int b = blk >> 9;
  int n0 = (blk & 511) * 32;
  float Gl = G[b * 64 + lane];
  const int* e0 = ei + (size_t)b * (NNODES * 16);                       // edge_index[0]
  const int* e1 = ei + (size_t)2 * NNODES * 16 + (size_t)b * (NNODES * 16);  // edge_index[1]
  const _Float16* ub = u + (size_t)b * NNODES * NCH + lane;
  const _Float16* vb = v + (size_t)b * NNODES * NCH + lane;
#pragma unroll 2
  for (int i = 0; i < 8; ++i) {
    int n = n0 + wv * 8 + i;
    const int* p0 = e0 + n * 16;
    const int* p1 = e1 + n * 16;
    float acc = -1e30f;
#pragma unroll
    for (int k = 0; k < 16; ++k) {
      int m1 = p1[k];
      int m0 = p0[k];
      float val = (float)ub[(size_t)m1 * NCH] + (float)vb[(size_t)m0 * NCH];
      acc = fmaxf(acc, val);
    }
    tile[lane][wv * 8 + i] = fmaxf(acc + Gl, 0.0f);
  }
  __syncthreads();
#pragma unroll
  for (int i = 0; i < 8; ++i) {
    int elem = t + i * 256;  // 0..2047 over 64o x 32n
    int o = elem >> 5;
    int nn = elem & 31;
    out[((size_t)b * 64 + o) * NNODES + n0 + nn] = tile[o][nn];
  }
}

extern "C" void kernel_launch(void* const* d_in, const int* in_sizes, int n_in,
                              void* d_out, int out_size, void* d_ws, size_t ws_size,
                              hipStream_t stream) {
  const float* x = (const float*)d_in[0];
  const int* ei = (const int*)d_in[1];   // harness contract: integer -> const int*
  const float* W = (const float*)d_in[2];
  const float* bias = (const float*)d_in[3];
  float* out = (float*)d_out;

  char* ws = (char*)d_ws;
  _Float16* u = (_Float16*)ws;                                  // 4 MiB
  _Float16* v = (_Float16*)(ws + (size_t)4 * 1024 * 1024);      // 4 MiB
  float* g = (float*)(ws + (size_t)8 * 1024 * 1024);            // 128 floats
  float* G = g + 256;                                           // 128 floats

  mean_kernel<<<128, 256, 0, stream>>>(x, g);
  gmat_kernel<<<1, 128, 0, stream>>>(W, bias, g, G);
  uv_kernel<<<1024, 256, 0, stream>>>(x, W, u, v);
  gather_kernel<<<1024, 256, 0, stream>>>(ei, u, v, G, out);
}

// Round 2
// 96.676 us; speedup vs baseline: 1.1970x; 1.1970x over previous
//
#include <hip/hip_runtime.h>
#include <hip/hip_bf16.h>

// B=2, C=64, N=16384, K=16, C_OUT=64
// out[b,o,n] = relu( max_k( u[b,e1[b,n,k],o] + v[b,e0[b,n,k],o] ) + G[b,o] )
//   u = (W1-W2)-transform of x per node, v = W2-transform, G = W3*mean(x)+bias
//
// Workspace layout:
//   [0, 4Mi)      u : _Float16 [B][N][64]
//   [4Mi, 8Mi)    v : _Float16 [B][N][64]
//   [8Mi, ...)    g : float[256 pad] (per b,c mean), then G : float[128]

#define NNODES 16384
#define NCH 64

typedef _Float16 half4 __attribute__((ext_vector_type(4)));

// ---------- K1: per-(b,c) mean over N ----------
__global__ __launch_bounds__(256) void mean_kernel(const float* __restrict__ x,
                                                   float* __restrict__ g) {
  int row = blockIdx.x;  // 0..127 = b*64+c
  const float4* x4 = (const float4*)(x + (size_t)row * NNODES);
  int t = threadIdx.x;
  float s = 0.f;
#pragma unroll
  for (int i = 0; i < 16; ++i) {
    float4 q = x4[t + i * 256];
    s += (q.x + q.y) + (q.z + q.w);
  }
#pragma unroll
  for (int off = 32; off > 0; off >>= 1) s += __shfl_down(s, off, 64);
  __shared__ float wsum[4];
  int lane = t & 63, wv = t >> 6;
  if (lane == 0) wsum[wv] = s;
  __syncthreads();
  if (t == 0) g[row] = (wsum[0] + wsum[1] + wsum[2] + wsum[3]) * (1.0f / 16384.0f);
}

// ---------- K2: G[b,o] = sum_c W3[o,c]*g[b,c] + bias[o] ----------
__global__ __launch_bounds__(128) void gmat_kernel(const float* __restrict__ W,
                                                   const float* __restrict__ bias,
                                                   const float* __restrict__ g,
                                                   float* __restrict__ G) {
  int t = threadIdx.x;  // 0..127 = b*64+o
  int b = t >> 6, o = t & 63;
  float s = bias[o];
  const float* w3 = W + o * 192 + 128;
  const float* gb = g + b * 64;
#pragma unroll
  for (int c = 0; c < 64; ++c) s += w3[c] * gb[c];
  G[t] = s;
}

// ---------- K3: u/v node transform ----------
// grid = B * (N/32) = 1024 blocks, 256 threads (4 waves), wave handles 8 nodes,
// lanes over output channel o. Weights staged transposed in LDS (conflict-free
// broadcast-free reads); x reads are wave-uniform float4 (scalar-load path).
__global__ __launch_bounds__(256) void uv_kernel(const float* __restrict__ x,
                                                 const float* __restrict__ W,
                                                 _Float16* __restrict__ u,
                                                 _Float16* __restrict__ v) {
  __shared__ float A[64][64];   // A[c][o]  = W1[o][c] - W2[o][c]
  __shared__ float Bm[64][64];  // Bm[c][o] = W2[o][c]
  int t = threadIdx.x;
  {
    int o = t & 63, c0 = (t >> 6) * 16;
    const float* wr = W + o * 192;
#pragma unroll
    for (int i = 0; i < 16; ++i) {
      int c = c0 + i;
      float w1 = wr[c], w2 = wr[64 + c];
      A[c][o] = w1 - w2;
      Bm[c][o] = w2;
    }
  }
  __syncthreads();
  int lane = t & 63;
  int wv = __builtin_amdgcn_readfirstlane(t >> 6);
  int blk = blockIdx.x;          // 0..1023
  int b = blk >> 9;              // 512 blocks per batch
  int m0 = (blk & 511) * 32 + wv * 8;  // wave's 8 nodes
  const float* xb = x + (size_t)b * (NCH * NNODES) + m0;
  float aU[8], aV[8];
#pragma unroll
  for (int i = 0; i < 8; ++i) { aU[i] = 0.f; aV[i] = 0.f; }
#pragma unroll 8
  for (int c = 0; c < 64; ++c) {
    float a = A[c][lane];
    float bb = Bm[c][lane];
    const float4* xr = (const float4*)(xb + (size_t)c * NNODES);
    float4 q0 = xr[0];
    float4 q1 = xr[1];
    aU[0] += a * q0.x; aV[0] += bb * q0.x;
    aU[1] += a * q0.y; aV[1] += bb * q0.y;
    aU[2] += a * q0.z; aV[2] += bb * q0.z;
    aU[3] += a * q0.w; aV[3] += bb * q0.w;
    aU[4] += a * q1.x; aV[4] += bb * q1.x;
    aU[5] += a * q1.y; aV[5] += bb * q1.y;
    aU[6] += a * q1.z; aV[6] += bb * q1.z;
    aU[7] += a * q1.w; aV[7] += bb * q1.w;
  }
  _Float16* ub = u + ((size_t)b * NNODES + m0) * NCH + lane;
  _Float16* vb = v + ((size_t)b * NNODES + m0) * NCH + lane;
#pragma unroll
  for (int i = 0; i < 8; ++i) {
    ub[i * NCH] = (_Float16)aU[i];
    vb[i * NCH] = (_Float16)aV[i];
  }
}

// ---------- K4: gather + max + relu, transpose to [b][o][n] ----------
// grid = B * (N/16) = 2048 blocks, 256 threads (4 waves).
// Wave covers 4 nodes: 16 lanes per node, each lane owns 4 channels (half4,
// 8B loads -> 128B coalesced segment per node). Packed fp16 add/max.
// XCD swizzle: blockIdx%8 is the XCD; XCDs 0-3 -> batch 0, 4-7 -> batch 1 so
// each XCD's gather working set (u_b+v_b = 4MB) fits its private 4MB L2.
__global__ __launch_bounds__(256) void gather_kernel(const int* __restrict__ ei,
                                                     const _Float16* __restrict__ u,
                                                     const _Float16* __restrict__ v,
                                                     const float* __restrict__ G,
                                                     float* __restrict__ out) {
  __shared__ float tile[64][17];
  int t = threadIdx.x;
  int lane = t & 63;
  int wv = t >> 6;                   // 0..3
  int blk = blockIdx.x;              // 0..2047
  int xcd = blk & 7;
  int b = xcd >> 2;                  // batch pinned to XCD group
  int nb = (blk >> 3) * 4 + (xcd & 3);  // 0..1023
  int n0 = nb * 16;                  // block's 16 nodes
  int node_q = lane >> 4;            // 0..3: node within wave
  int k_l = lane & 15;               // dual use: k for index preload, ch-quad for gather
  int n = n0 + wv * 4 + node_q;
  const int* e0b = ei + (size_t)b * NNODES * 16;        // edge_index[0][b]
  const int* e1b = ei + (size_t)(2 + b) * NNODES * 16;  // edge_index[1][b]
  // coalesced 256B index preload: lane = node_q*16 + k
  int idx0 = e0b[n * 16 + k_l];
  int idx1 = e1b[n * 16 + k_l];
  int c4 = k_l * 4;  // this lane's channel base
  const half4* ub = (const half4*)(u + (size_t)b * NNODES * NCH + c4);
  const half4* vb = (const half4*)(v + (size_t)b * NNODES * NCH + c4);
  half4 acc;
  acc.x = acc.y = acc.z = acc.w = (_Float16)(-60000.0f);
#pragma unroll
  for (int k = 0; k < 16; ++k) {
    int src = (lane & 48) + k;       // node_q*16 + k
    int m1 = __shfl(idx1, src, 64);
    int m0 = __shfl(idx0, src, 64);
    half4 a = ub[(size_t)m1 * 16];   // *16 half4 = *64 elements
    half4 bb = vb[(size_t)m0 * 16];
    half4 s = a + bb;                // v_pk_add_f16 x2
    acc = __builtin_elementwise_max(acc, s);  // v_pk_max_f16 x2
  }
  float4 Gl = *(const float4*)(G + b * 64 + c4);
  int nn = wv * 4 + node_q;          // 0..15: column in tile
  tile[c4 + 0][nn] = fmaxf((float)acc.x + Gl.x, 0.0f);
  tile[c4 + 1][nn] = fmaxf((float)acc.y + Gl.y, 0.0f);
  tile[c4 + 2][nn] = fmaxf((float)acc.z + Gl.z, 0.0f);
  tile[c4 + 3][nn] = fmaxf((float)acc.w + Gl.w, 0.0f);
  __syncthreads();
  // out writes: 16 consecutive floats per (b,o) row segment
  int col = t & 15;
  int orow = t >> 4;  // 0..15
#pragma unroll
  for (int j = 0; j < 4; ++j) {
    int o = orow + j * 16;
    out[((size_t)b * 64 + o) * NNODES + n0 + col] = tile[o][col];
  }
}

extern "C" void kernel_launch(void* const* d_in, const int* in_sizes, int n_in,
                              void* d_out, int out_size, void* d_ws, size_t ws_size,
                              hipStream_t stream) {
  const float* x = (const float*)d_in[0];
  const int* ei = (const int*)d_in[1];
  const float* W = (const float*)d_in[2];
  const float* bias = (const float*)d_in[3];
  float* out = (float*)d_out;

  char* ws = (char*)d_ws;
  _Float16* u = (_Float16*)ws;                               // 4 MiB
  _Float16* v = (_Float16*)(ws + (size_t)4 * 1024 * 1024);   // 4 MiB
  float* g = (float*)(ws + (size_t)8 * 1024 * 1024);         // 128 floats (256 pad)
  float* G = g + 256;                                        // 128 floats, 16B aligned

  mean_kernel<<<128, 256, 0, stream>>>(x, g);
  gmat_kernel<<<1, 128, 0, stream>>>(W, bias, g, G);
  uv_kernel<<<1024, 256, 0, stream>>>(x, W, u, v);
  gather_kernel<<<2048, 256, 0, stream>>>(ei, u, v, G, out);
}

// Round 3
// 93.590 us; speedup vs baseline: 1.2365x; 1.0330x over previous
//
#include <hip/hip_runtime.h>
#include <hip/hip_bf16.h>

// B=2, C=64, N=16384, K=16, C_OUT=64
// out[b,o,n] = relu( max_k( u[b,e1[b,n,k],o] + v[b,e0[b,n,k],o] ) + G[b,o] )
//   u = (W1-W2)-transform of x per node, v = W2-transform, G = W3*mean(x)+bias
//
// Workspace layout:
//   [0, 4Mi)      u : _Float16 [B][N][64]   (node-major: one node = 128B line)
//   [4Mi, 8Mi)    v : _Float16 [B][N][64]
//   [8Mi, ...)    g : float[256 pad] (per b,c mean of x over nodes)

#define NNODES 16384
#define NCH 64

typedef _Float16 half8 __attribute__((ext_vector_type(8)));

// ---------- K1: per-(b,c) mean over N ----------
__global__ __launch_bounds__(256) void mean_kernel(const float* __restrict__ x,
                                                   float* __restrict__ g) {
  int row = blockIdx.x;  // 0..127 = b*64+c
  const float4* x4 = (const float4*)(x + (size_t)row * NNODES);
  int t = threadIdx.x;
  float s = 0.f;
#pragma unroll
  for (int i = 0; i < 16; ++i) {
    float4 q = x4[t + i * 256];
    s += (q.x + q.y) + (q.z + q.w);
  }
#pragma unroll
  for (int off = 32; off > 0; off >>= 1) s += __shfl_down(s, off, 64);
  __shared__ float wsum[4];
  int lane = t & 63, wv = t >> 6;
  if (lane == 0) wsum[wv] = s;
  __syncthreads();
  if (t == 0) g[row] = (wsum[0] + wsum[1] + wsum[2] + wsum[3]) * (1.0f / 16384.0f);
}

// ---------- K2: u/v node transform ----------
// grid = B * (N/32) = 1024 blocks, 256 threads (4 waves), wave handles 8 nodes,
// lanes over output channel o. Weights staged transposed in LDS (conflict-free
// reads); x reads are wave-uniform float4 (scalar-load path).
__global__ __launch_bounds__(256) void uv_kernel(const float* __restrict__ x,
                                                 const float* __restrict__ W,
                                                 _Float16* __restrict__ u,
                                                 _Float16* __restrict__ v) {
  __shared__ float A[64][64];   // A[c][o]  = W1[o][c] - W2[o][c]
  __shared__ float Bm[64][64];  // Bm[c][o] = W2[o][c]
  int t = threadIdx.x;
  {
    int o = t & 63, c0 = (t >> 6) * 16;
    const float* wr = W + o * 192;
#pragma unroll
    for (int i = 0; i < 16; ++i) {
      int c = c0 + i;
      float w1 = wr[c], w2 = wr[64 + c];
      A[c][o] = w1 - w2;
      Bm[c][o] = w2;
    }
  }
  __syncthreads();
  int lane = t & 63;
  int wv = __builtin_amdgcn_readfirstlane(t >> 6);
  int blk = blockIdx.x;          // 0..1023
  int b = blk >> 9;              // 512 blocks per batch
  int m0 = (blk & 511) * 32 + wv * 8;  // wave's 8 nodes
  const float* xb = x + (size_t)b * (NCH * NNODES) + m0;
  float aU[8], aV[8];
#pragma unroll
  for (int i = 0; i < 8; ++i) { aU[i] = 0.f; aV[i] = 0.f; }
#pragma unroll 8
  for (int c = 0; c < 64; ++c) {
    float a = A[c][lane];
    float bb = Bm[c][lane];
    const float4* xr = (const float4*)(xb + (size_t)c * NNODES);
    float4 q0 = xr[0];
    float4 q1 = xr[1];
    aU[0] += a * q0.x; aV[0] += bb * q0.x;
    aU[1] += a * q0.y; aV[1] += bb * q0.y;
    aU[2] += a * q0.z; aV[2] += bb * q0.z;
    aU[3] += a * q0.w; aV[3] += bb * q0.w;
    aU[4] += a * q1.x; aV[4] += bb * q1.x;
    aU[5] += a * q1.y; aV[5] += bb * q1.y;
    aU[6] += a * q1.z; aV[6] += bb * q1.z;
    aU[7] += a * q1.w; aV[7] += bb * q1.w;
  }
  _Float16* ub = u + ((size_t)b * NNODES + m0) * NCH + lane;
  _Float16* vb = v + ((size_t)b * NNODES + m0) * NCH + lane;
#pragma unroll
  for (int i = 0; i < 8; ++i) {
    ub[i * NCH] = (_Float16)aU[i];
    vb[i * NCH] = (_Float16)aV[i];
  }
}

// ---------- K3: G + gather + max + relu, transpose to [b][o][n] ----------
// grid = B * (N/32) = 1024 blocks, 256 threads (4 waves).
// Wave covers 8 nodes: 8 lanes/node, each lane owns 8 channels (half8 = 16B
// loads; a node's 64 fp16 = one aligned 128B line; 1KB per wave-instruction).
// G = W3*mean(x)+bias computed redundantly per block (fused, removes the gmat
// dispatch) while index loads are in flight. Packed fp16 add/max.
// XCD swizzle: blockIdx%8 is the XCD; XCDs 0-3 -> batch 0, 4-7 -> batch 1 so
// each XCD's gather working set (u_b+v_b = 4MB) fits its private 4MB L2.
__global__ __launch_bounds__(256) void gather_kernel(const int* __restrict__ ei,
                                                     const _Float16* __restrict__ u,
                                                     const _Float16* __restrict__ v,
                                                     const float* __restrict__ W,
                                                     const float* __restrict__ bias,
                                                     const float* __restrict__ g,
                                                     float* __restrict__ out) {
  __shared__ float tile[64][33];
  __shared__ float pg[4][64];
  __shared__ float G_s[64];
  int t = threadIdx.x;
  int lane = t & 63;
  int wv = t >> 6;                      // 0..3
  int blk = blockIdx.x;                 // 0..1023
  int xcd = blk & 7;
  int b = xcd >> 2;                     // batch pinned to XCD group
  int nb = (blk >> 3) * 4 + (xcd & 3);  // 0..511
  int n0 = nb * 32;                     // block's 32 nodes
  int q = lane >> 3;                    // node within wave 0..7
  int r = lane & 7;                     // channel-octet 0..7
  const int* e0b = ei + (size_t)b * NNODES * 16;        // edge_index[0][b]
  const int* e1b = ei + (size_t)(2 + b) * NNODES * 16;  // edge_index[1][b]
  // Index preload: lane (q,r) holds k=r and k=r+8 for its node q.
  int f0 = (n0 + wv * 8) * 16 + q * 16 + r;
  int i0a = e0b[f0];
  int i0b = e0b[f0 + 8];
  int i1a = e1b[f0];
  int i1b = e1b[f0 + 8];
  // ---- fused G = W3*g_b + bias (overlaps the index-load latency) ----
  {
    int o = t >> 2, cq = t & 3;
    const float4* wr = (const float4*)(W + o * 192 + 128 + cq * 16);
    const float4* gr = (const float4*)(g + b * 64 + cq * 16);
    float s = 0.f;
#pragma unroll
    for (int j = 0; j < 4; ++j) {
      float4 w = wr[j];
      float4 gg = gr[j];
      s += w.x * gg.x + w.y * gg.y + w.z * gg.z + w.w * gg.w;
    }
    pg[cq][o] = s;
  }
  __syncthreads();
  if (t < 64) G_s[t] = bias[t] + ((pg[0][t] + pg[1][t]) + (pg[2][t] + pg[3][t]));
  __syncthreads();
  // ---- gather + running max ----
  const half8* u8 = (const half8*)(u + (size_t)b * NNODES * NCH) + r;
  const half8* v8 = (const half8*)(v + (size_t)b * NNODES * NCH) + r;
  half8 acc;
#pragma unroll
  for (int j = 0; j < 8; ++j) acc[j] = (_Float16)(-60000.0f);
#pragma unroll
  for (int k = 0; k < 16; ++k) {
    int src = (lane & 56) + (k & 7);            // lane holding (my node q, k)
    int m1 = __shfl(k < 8 ? i1a : i1b, src, 64);  // register picked at compile time
    int m0 = __shfl(k < 8 ? i0a : i0b, src, 64);
    half8 a = u8[(size_t)m1 * 8];               // node m1's octet r (16B)
    half8 bb = v8[(size_t)m0 * 8];
    half8 s = a + bb;                           // v_pk_add_f16 x4
    acc = __builtin_elementwise_max(acc, s);    // v_pk_max_f16 x4
  }
  // ---- epilogue: +G, relu, LDS transpose ----
  int col = wv * 8 + q;  // node column 0..31
#pragma unroll
  for (int j = 0; j < 8; ++j) {
    tile[r * 8 + j][col] = fmaxf((float)acc[j] + G_s[r * 8 + j], 0.0f);
  }
  __syncthreads();
#pragma unroll
  for (int j = 0; j < 8; ++j) {
    int o = (t >> 5) + j * 8;
    int c2 = t & 31;
    out[((size_t)b * 64 + o) * NNODES + n0 + c2] = tile[o][c2];
  }
}

extern "C" void kernel_launch(void* const* d_in, const int* in_sizes, int n_in,
                              void* d_out, int out_size, void* d_ws, size_t ws_size,
                              hipStream_t stream) {
  const float* x = (const float*)d_in[0];
  const int* ei = (const int*)d_in[1];
  const float* W = (const float*)d_in[2];
  const float* bias = (const float*)d_in[3];
  float* out = (float*)d_out;

  char* ws = (char*)d_ws;
  _Float16* u = (_Float16*)ws;                               // 4 MiB
  _Float16* v = (_Float16*)(ws + (size_t)4 * 1024 * 1024);   // 4 MiB
  float* g = (float*)(ws + (size_t)8 * 1024 * 1024);         // 128 floats

  mean_kernel<<<128, 256, 0, stream>>>(x, g);
  uv_kernel<<<1024, 256, 0, stream>>>(x, W, u, v);
  gather_kernel<<<1024, 256, 0, stream>>>(ei, u, v, W, bias, g, out);
}

// Round 4
// 92.626 us; speedup vs baseline: 1.2493x; 1.0104x over previous
//
#include <hip/hip_runtime.h>
#include <hip/hip_bf16.h>

// B=2, C=64, N=16384, K=16, C_OUT=64
// out[b,o,n] = relu( max_k( u[b,e1[b,n,k],o] + v[b,e0[b,n,k],o] ) + G[b,o] )
//   u = (W1-W2)-transform of x per node, v = W2-transform, G = W3*mean(x)+bias
//
// Workspace layout:
//   [0, 4Mi)      u : _Float16 [B][N][64]   (node-major: one node = 128B line)
//   [4Mi, 8Mi)    v : _Float16 [B][N][64]
//   [8Mi, +4KiB)  g_slots : float[8][128]   (partial column sums, atomically
//                                            accumulated; memset to 0 first)

#define NNODES 16384
#define NCH 64

typedef _Float16 half8 __attribute__((ext_vector_type(8)));

// ---------- K1: u/v node transform + x column-sum (for the global mean) ----
// grid = B * (N/32) = 1024 blocks, 256 threads (4 waves), wave handles 8 nodes,
// lanes over output channel o. Weights staged transposed in LDS (conflict-free
// reads); x reads are wave-uniform float4 (scalar-load path).
// After the main loop each block re-reads its (L1/L2-hot) 8KB x-slice with a
// transposed mapping, reduces per-channel sums over its 32 nodes, and does one
// atomicAdd per channel into g_slots[blk&7][...] (8 slots spread contention).
__global__ __launch_bounds__(256) void uv_kernel(const float* __restrict__ x,
                                                 const float* __restrict__ W,
                                                 _Float16* __restrict__ u,
                                                 _Float16* __restrict__ v,
                                                 float* __restrict__ g_slots) {
  __shared__ float A[64][64];   // A[c][o]  = W1[o][c] - W2[o][c]
  __shared__ float Bm[64][64];  // Bm[c][o] = W2[o][c]
  __shared__ float csum[4][64];
  int t = threadIdx.x;
  {
    int o = t & 63, c0 = (t >> 6) * 16;
    const float* wr = W + o * 192;
#pragma unroll
    for (int i = 0; i < 16; ++i) {
      int c = c0 + i;
      float w1 = wr[c], w2 = wr[64 + c];
      A[c][o] = w1 - w2;
      Bm[c][o] = w2;
    }
  }
  __syncthreads();
  int lane = t & 63;
  int wv = __builtin_amdgcn_readfirstlane(t >> 6);
  int blk = blockIdx.x;          // 0..1023
  int b = blk >> 9;              // 512 blocks per batch
  int mb = (blk & 511) * 32;     // block's 32 nodes
  int m0 = mb + wv * 8;          // wave's 8 nodes
  const float* xb = x + (size_t)b * (NCH * NNODES) + m0;
  float aU[8], aV[8];
#pragma unroll
  for (int i = 0; i < 8; ++i) { aU[i] = 0.f; aV[i] = 0.f; }
#pragma unroll 8
  for (int c = 0; c < 64; ++c) {
    float a = A[c][lane];
    float bb = Bm[c][lane];
    const float4* xr = (const float4*)(xb + (size_t)c * NNODES);
    float4 q0 = xr[0];
    float4 q1 = xr[1];
    aU[0] += a * q0.x; aV[0] += bb * q0.x;
    aU[1] += a * q0.y; aV[1] += bb * q0.y;
    aU[2] += a * q0.z; aV[2] += bb * q0.z;
    aU[3] += a * q0.w; aV[3] += bb * q0.w;
    aU[4] += a * q1.x; aV[4] += bb * q1.x;
    aU[5] += a * q1.y; aV[5] += bb * q1.y;
    aU[6] += a * q1.z; aV[6] += bb * q1.z;
    aU[7] += a * q1.w; aV[7] += bb * q1.w;
  }
  _Float16* ub = u + ((size_t)b * NNODES + m0) * NCH + lane;
  _Float16* vb = v + ((size_t)b * NNODES + m0) * NCH + lane;
#pragma unroll
  for (int i = 0; i < 8; ++i) {
    ub[i * NCH] = (_Float16)aU[i];
    vb[i * NCH] = (_Float16)aV[i];
  }
  // ---- column-sum pass (hot re-read of the block's x slice) ----
  {
    int c = t & 63, piece = t >> 6;  // piece covers 8 nodes
    const float4* xr2 =
        (const float4*)(x + (size_t)b * (NCH * NNODES) + (size_t)c * NNODES + mb + piece * 8);
    float4 a0 = xr2[0];
    float4 a1 = xr2[1];
    csum[piece][c] = ((a0.x + a0.y) + (a0.z + a0.w)) + ((a1.x + a1.y) + (a1.z + a1.w));
  }
  __syncthreads();
  if (t < 64) {
    float s = (csum[0][t] + csum[1][t]) + (csum[2][t] + csum[3][t]);
    atomicAdd(&g_slots[((blk & 7) << 7) + b * 64 + t], s);
  }
}

// ---------- K2: G + gather + max + relu, transpose to [b][o][n] ----------
// grid = B * (N/32) = 1024 blocks, 256 threads (4 waves).
// Wave covers 8 nodes: 8 lanes/node, each lane owns 8 channels (half8 = 16B
// loads; a node's 64 fp16 = one aligned 128B line; 1KB per wave-instruction).
// G = W3*mean(x)+bias computed redundantly per block from g_slots (L2-hot)
// while index loads are in flight. Packed fp16 add/max.
// XCD swizzle: blockIdx%8 is the XCD; XCDs 0-3 -> batch 0, 4-7 -> batch 1 so
// each XCD's gather working set (u_b+v_b = 4MB) fits its private 4MB L2.
__global__ __launch_bounds__(256) void gather_kernel(const int* __restrict__ ei,
                                                     const _Float16* __restrict__ u,
                                                     const _Float16* __restrict__ v,
                                                     const float* __restrict__ W,
                                                     const float* __restrict__ bias,
                                                     const float* __restrict__ g_slots,
                                                     float* __restrict__ out) {
  __shared__ float tile[64][33];
  __shared__ float gb[64];
  __shared__ float pg[4][64];
  __shared__ float G_s[64];
  int t = threadIdx.x;
  int lane = t & 63;
  int wv = t >> 6;                      // 0..3
  int blk = blockIdx.x;                 // 0..1023
  int xcd = blk & 7;
  int b = xcd >> 2;                     // batch pinned to XCD group
  int nb = (blk >> 3) * 4 + (xcd & 3);  // 0..511
  int n0 = nb * 32;                     // block's 32 nodes
  int q = lane >> 3;                    // node within wave 0..7
  int r = lane & 7;                     // channel-octet 0..7
  const int* e0b = ei + (size_t)b * NNODES * 16;        // edge_index[0][b]
  const int* e1b = ei + (size_t)(2 + b) * NNODES * 16;  // edge_index[1][b]
  // Index preload: lane (q,r) holds k=r and k=r+8 for its node q.
  int f0 = (n0 + wv * 8) * 16 + q * 16 + r;
  int i0a = e0b[f0];
  int i0b = e0b[f0 + 8];
  int i1a = e1b[f0];
  int i1b = e1b[f0 + 8];
  // ---- fused G = W3*(colsum/N) + bias (overlaps the index-load latency) ----
  if (t < 64) {
    float s = 0.f;
#pragma unroll
    for (int sl = 0; sl < 8; ++sl) s += g_slots[sl * 128 + b * 64 + t];
    gb[t] = s * (1.0f / 16384.0f);
  }
  __syncthreads();
  {
    int o = t >> 2, cq = t & 3;
    const float4* wr = (const float4*)(W + o * 192 + 128 + cq * 16);
    const float4* gr = (const float4*)(gb + cq * 16);
    float s = 0.f;
#pragma unroll
    for (int j = 0; j < 4; ++j) {
      float4 w = wr[j];
      float4 gg = gr[j];
      s += w.x * gg.x + w.y * gg.y + w.z * gg.z + w.w * gg.w;
    }
    pg[cq][o] = s;
  }
  __syncthreads();
  if (t < 64) G_s[t] = bias[t] + ((pg[0][t] + pg[1][t]) + (pg[2][t] + pg[3][t]));
  __syncthreads();
  // ---- gather + running max ----
  const half8* u8 = (const half8*)(u + (size_t)b * NNODES * NCH) + r;
  const half8* v8 = (const half8*)(v + (size_t)b * NNODES * NCH) + r;
  half8 acc;
#pragma unroll
  for (int j = 0; j < 8; ++j) acc[j] = (_Float16)(-60000.0f);
#pragma unroll
  for (int k = 0; k < 16; ++k) {
    int src = (lane & 56) + (k & 7);              // lane holding (my node q, k)
    int m1 = __shfl(k < 8 ? i1a : i1b, src, 64);  // register picked at compile time
    int m0 = __shfl(k < 8 ? i0a : i0b, src, 64);
    half8 a = u8[(size_t)m1 * 8];                 // node m1's octet r (16B)
    half8 bb = v8[(size_t)m0 * 8];
    half8 s = a + bb;                             // v_pk_add_f16 x4
    acc = __builtin_elementwise_max(acc, s);      // v_pk_max_f16 x4
  }
  // ---- epilogue: +G, relu, LDS transpose ----
  int col = wv * 8 + q;  // node column 0..31
#pragma unroll
  for (int j = 0; j < 8; ++j) {
    tile[r * 8 + j][col] = fmaxf((float)acc[j] + G_s[r * 8 + j], 0.0f);
  }
  __syncthreads();
#pragma unroll
  for (int j = 0; j < 8; ++j) {
    int o = (t >> 5) + j * 8;
    int c2 = t & 31;
    out[((size_t)b * 64 + o) * NNODES + n0 + c2] = tile[o][c2];
  }
}

extern "C" void kernel_launch(void* const* d_in, const int* in_sizes, int n_in,
                              void* d_out, int out_size, void* d_ws, size_t ws_size,
                              hipStream_t stream) {
  const float* x = (const float*)d_in[0];
  const int* ei = (const int*)d_in[1];
  const float* W = (const float*)d_in[2];
  const float* bias = (const float*)d_in[3];
  float* out = (float*)d_out;

  char* ws = (char*)d_ws;
  _Float16* u = (_Float16*)ws;                               // 4 MiB
  _Float16* v = (_Float16*)(ws + (size_t)4 * 1024 * 1024);   // 4 MiB
  float* g_slots = (float*)(ws + (size_t)8 * 1024 * 1024);   // 8*128 floats

  hipMemsetAsync(g_slots, 0, 8 * 128 * sizeof(float), stream);
  uv_kernel<<<1024, 256, 0, stream>>>(x, W, u, v, g_slots);
  gather_kernel<<<1024, 256, 0, stream>>>(ei, u, v, W, bias, g_slots, out);
}

// Round 5
// 91.818 us; speedup vs baseline: 1.2603x; 1.0088x over previous
//
#include <hip/hip_runtime.h>
#include <hip/hip_bf16.h>

// B=2, C=64, N=16384, K=16, C_OUT=64
// out[b,o,n] = relu( max_k( u[b,e1[b,n,k],o] + v[b,e0[b,n,k],o] ) + G[b,o] )
//   u = (W1-W2)-transform of x per node, v = W2-transform, G = W3*mean(x)+bias
//
// Workspace layout:
//   [0, 4Mi)      u : _Float16 [B][N][64]   (node-major: one node = 128B line)
//   [4Mi, 8Mi)    v : _Float16 [B][N][64]
//   [8Mi, +4KiB)  g_slots : float[8][128]   (partial column sums, atomically
//                                            accumulated; memset to 0 first)

#define NNODES 16384
#define NCH 64

typedef _Float16 half8 __attribute__((ext_vector_type(8)));
typedef float f32x2 __attribute__((ext_vector_type(2)));

// ---------- K1: u/v node transform + x column-sum (for the global mean) ----
// grid = B * (N/32) = 1024 blocks, 256 threads (4 waves), wave handles 8 nodes,
// lanes over output channel o. Weights staged transposed in LDS (conflict-free
// reads); x reads are wave-uniform float4 (scalar-load path).
// Accumulators are float2 so the 16 FMAs/channel emit 8 v_pk_fma_f32 (2x rate).
// After the main loop each block re-reads its (L1/L2-hot) 8KB x-slice with a
// transposed mapping, reduces per-channel sums over its 32 nodes, and does one
// atomicAdd per channel into g_slots[blk&7][...] (8 slots spread contention).
__global__ __launch_bounds__(256) void uv_kernel(const float* __restrict__ x,
                                                 const float* __restrict__ W,
                                                 _Float16* __restrict__ u,
                                                 _Float16* __restrict__ v,
                                                 float* __restrict__ g_slots) {
  __shared__ float A[64][64];   // A[c][o]  = W1[o][c] - W2[o][c]
  __shared__ float Bm[64][64];  // Bm[c][o] = W2[o][c]
  __shared__ float csum[4][64];
  int t = threadIdx.x;
  {
    int o = t & 63, c0 = (t >> 6) * 16;
    const float* wr = W + o * 192;
#pragma unroll
    for (int i = 0; i < 16; ++i) {
      int c = c0 + i;
      float w1 = wr[c], w2 = wr[64 + c];
      A[c][o] = w1 - w2;
      Bm[c][o] = w2;
    }
  }
  __syncthreads();
  int lane = t & 63;
  int wv = __builtin_amdgcn_readfirstlane(t >> 6);
  int blk = blockIdx.x;          // 0..1023
  int b = blk >> 9;              // 512 blocks per batch
  int mb = (blk & 511) * 32;     // block's 32 nodes
  int m0 = mb + wv * 8;          // wave's 8 nodes
  const float* xb = x + (size_t)b * (NCH * NNODES) + m0;
  f32x2 aU[4], aV[4];
#pragma unroll
  for (int i = 0; i < 4; ++i) {
    aU[i] = (f32x2){0.f, 0.f};
    aV[i] = (f32x2){0.f, 0.f};
  }
#pragma unroll 8
  for (int c = 0; c < 64; ++c) {
    float a = A[c][lane];
    float bb = Bm[c][lane];
    f32x2 a2 = {a, a};
    f32x2 b2 = {bb, bb};
    const float4* xr = (const float4*)(xb + (size_t)c * NNODES);
    float4 q0 = xr[0];
    float4 q1 = xr[1];
    f32x2 p0 = {q0.x, q0.y};
    f32x2 p1 = {q0.z, q0.w};
    f32x2 p2 = {q1.x, q1.y};
    f32x2 p3 = {q1.z, q1.w};
    aU[0] = __builtin_elementwise_fma(a2, p0, aU[0]);
    aU[1] = __builtin_elementwise_fma(a2, p1, aU[1]);
    aU[2] = __builtin_elementwise_fma(a2, p2, aU[2]);
    aU[3] = __builtin_elementwise_fma(a2, p3, aU[3]);
    aV[0] = __builtin_elementwise_fma(b2, p0, aV[0]);
    aV[1] = __builtin_elementwise_fma(b2, p1, aV[1]);
    aV[2] = __builtin_elementwise_fma(b2, p2, aV[2]);
    aV[3] = __builtin_elementwise_fma(b2, p3, aV[3]);
  }
  _Float16* ub = u + ((size_t)b * NNODES + m0) * NCH + lane;
  _Float16* vb = v + ((size_t)b * NNODES + m0) * NCH + lane;
#pragma unroll
  for (int i = 0; i < 4; ++i) {
    ub[(2 * i) * NCH] = (_Float16)aU[i][0];
    ub[(2 * i + 1) * NCH] = (_Float16)aU[i][1];
    vb[(2 * i) * NCH] = (_Float16)aV[i][0];
    vb[(2 * i + 1) * NCH] = (_Float16)aV[i][1];
  }
  // ---- column-sum pass (hot re-read of the block's x slice) ----
  {
    int c = t & 63, piece = t >> 6;  // piece covers 8 nodes
    const float4* xr2 =
        (const float4*)(x + (size_t)b * (NCH * NNODES) + (size_t)c * NNODES + mb + piece * 8);
    float4 a0 = xr2[0];
    float4 a1 = xr2[1];
    csum[piece][c] = ((a0.x + a0.y) + (a0.z + a0.w)) + ((a1.x + a1.y) + (a1.z + a1.w));
  }
  __syncthreads();
  if (t < 64) {
    float s = (csum[0][t] + csum[1][t]) + (csum[2][t] + csum[3][t]);
    atomicAdd(&g_slots[((blk & 7) << 7) + b * 64 + t], s);
  }
}

// ---------- K2: G + gather + max + relu, transpose to [b][o][n] ----------
// grid = B * (N/32) = 1024 blocks, 256 threads (4 waves).
// Wave covers 8 nodes: 8 lanes/node, each lane owns 8 channels (half8 = 16B
// loads; a node's 64 fp16 = one aligned 128B line; 1KB per wave-instruction).
// G = W3*mean(x)+bias computed redundantly per block from g_slots (L2-hot)
// while index loads are in flight. Packed fp16 add/max.
// XCD swizzle: blockIdx%8 is the XCD; XCDs 0-3 -> batch 0, 4-7 -> batch 1 so
// each XCD's gather working set (u_b+v_b = 4MB) fits its private 4MB L2.
__global__ __launch_bounds__(256) void gather_kernel(const int* __restrict__ ei,
                                                     const _Float16* __restrict__ u,
                                                     const _Float16* __restrict__ v,
                                                     const float* __restrict__ W,
                                                     const float* __restrict__ bias,
                                                     const float* __restrict__ g_slots,
                                                     float* __restrict__ out) {
  __shared__ float tile[64][33];
  __shared__ float gb[64];
  __shared__ float pg[4][64];
  __shared__ float G_s[64];
  int t = threadIdx.x;
  int lane = t & 63;
  int wv = t >> 6;                      // 0..3
  int blk = blockIdx.x;                 // 0..1023
  int xcd = blk & 7;
  int b = xcd >> 2;                     // batch pinned to XCD group
  int nb = (blk >> 3) * 4 + (xcd & 3);  // 0..511
  int n0 = nb * 32;                     // block's 32 nodes
  int q = lane >> 3;                    // node within wave 0..7
  int r = lane & 7;                     // channel-octet 0..7
  const int* e0b = ei + (size_t)b * NNODES * 16;        // edge_index[0][b]
  const int* e1b = ei + (size_t)(2 + b) * NNODES * 16;  // edge_index[1][b]
  // Index preload: lane (q,r) holds k=r and k=r+8 for its node q.
  int f0 = (n0 + wv * 8) * 16 + q * 16 + r;
  int i0a = e0b[f0];
  int i0b = e0b[f0 + 8];
  int i1a = e1b[f0];
  int i1b = e1b[f0 + 8];
  // ---- fused G = W3*(colsum/N) + bias (overlaps the index-load latency) ----
  if (t < 64) {
    float s = 0.f;
#pragma unroll
    for (int sl = 0; sl < 8; ++sl) s += g_slots[sl * 128 + b * 64 + t];
    gb[t] = s * (1.0f / 16384.0f);
  }
  __syncthreads();
  {
    int o = t >> 2, cq = t & 3;
    const float4* wr = (const float4*)(W + o * 192 + 128 + cq * 16);
    const float4* gr = (const float4*)(gb + cq * 16);
    float s = 0.f;
#pragma unroll
    for (int j = 0; j < 4; ++j) {
      float4 w = wr[j];
      float4 gg = gr[j];
      s += w.x * gg.x + w.y * gg.y + w.z * gg.z + w.w * gg.w;
    }
    pg[cq][o] = s;
  }
  __syncthreads();
  if (t < 64) G_s[t] = bias[t] + ((pg[0][t] + pg[1][t]) + (pg[2][t] + pg[3][t]));
  __syncthreads();
  // ---- gather + running max ----
  const half8* u8 = (const half8*)(u + (size_t)b * NNODES * NCH) + r;
  const half8* v8 = (const half8*)(v + (size_t)b * NNODES * NCH) + r;
  half8 acc;
#pragma unroll
  for (int j = 0; j < 8; ++j) acc[j] = (_Float16)(-60000.0f);
#pragma unroll
  for (int k = 0; k < 16; ++k) {
    int src = (lane & 56) + (k & 7);              // lane holding (my node q, k)
    int m1 = __shfl(k < 8 ? i1a : i1b, src, 64);  // register picked at compile time
    int m0 = __shfl(k < 8 ? i0a : i0b, src, 64);
    half8 a = u8[(size_t)m1 * 8];                 // node m1's octet r (16B)
    half8 bb = v8[(size_t)m0 * 8];
    half8 s = a + bb;                             // v_pk_add_f16 x4
    acc = __builtin_elementwise_max(acc, s);      // v_pk_max_f16 x4
  }
  // ---- epilogue: +G, relu, LDS transpose ----
  int col = wv * 8 + q;  // node column 0..31
#pragma unroll
  for (int j = 0; j < 8; ++j) {
    tile[r * 8 + j][col] = fmaxf((float)acc[j] + G_s[r * 8 + j], 0.0f);
  }
  __syncthreads();
#pragma unroll
  for (int j = 0; j < 8; ++j) {
    int o = (t >> 5) + j * 8;
    int c2 = t & 31;
    out[((size_t)b * 64 + o) * NNODES + n0 + c2] = tile[o][c2];
  }
}

extern "C" void kernel_launch(void* const* d_in, const int* in_sizes, int n_in,
                              void* d_out, int out_size, void* d_ws, size_t ws_size,
                              hipStream_t stream) {
  const float* x = (const float*)d_in[0];
  const int* ei = (const int*)d_in[1];
  const float* W = (const float*)d_in[2];
  const float* bias = (const float*)d_in[3];
  float* out = (float*)d_out;

  char* ws = (char*)d_ws;
  _Float16* u = (_Float16*)ws;                               // 4 MiB
  _Float16* v = (_Float16*)(ws + (size_t)4 * 1024 * 1024);   // 4 MiB
  float* g_slots = (float*)(ws + (size_t)8 * 1024 * 1024);   // 8*128 floats

  hipMemsetAsync(g_slots, 0, 8 * 128 * sizeof(float), stream);
  uv_kernel<<<1024, 256, 0, stream>>>(x, W, u, v, g_slots);
  gather_kernel<<<1024, 256, 0, stream>>>(ei, u, v, W, bias, g_slots, out);
}